// Round 3
// baseline (267.719 us; speedup 1.0000x reference)
//
#include <hip/hip_runtime.h>
#include <hip/hip_bf16.h>

// out[v,g,u,d] = W[GE[v,g] % 3, d] + b[d], out shape [V=512, G=4, V=512, D=64] fp32.
// Pure write-BW bound: 256 MiB of stores, ~8 KB of reads.
// One block per (v,g): computes its 64-float row once, streams V*D floats
// with non-temporal (nt) float4 stores to avoid L3 write-allocate churn
// (d_out is 256 MiB == Infinity Cache capacity).

#define V 512
#define G 4
#define D 64
#define D4 (D / 4)  // 16 float4 per row

typedef float fx4 __attribute__((ext_vector_type(4)));  // native vec type for nt-store

__global__ __launch_bounds__(256) void gembed_kernel(
    const int* __restrict__ GE,      // [V*G] int32, values in [0,3)
    const float* __restrict__ W,     // [3, D]
    const float* __restrict__ b,     // [D]
    float* __restrict__ out)         // [V*G*V*D]
{
    const int bid = blockIdx.x;          // (v*G + g) in [0, V*G)
    const int tid = threadIdx.x;         // 0..255
    const int d4  = tid & (D4 - 1);      // which float4 within the D row
    const int u0  = tid >> 4;            // starting u-row (0..15)

    int e = GE[bid];
    e = ((e % 3) + 3) % 3;               // safety; values are already 0..2

    const fx4* __restrict__ W4 = (const fx4*)W;  // [3 * D4]
    const fx4* __restrict__ b4 = (const fx4*)b;  // [D4]

    fx4 val = W4[e * D4 + d4] + b4[d4];

    // Block writes V rows of D floats = V * D4 float4s, contiguous (128 KB).
    fx4* __restrict__ out4 = (fx4*)out + (size_t)bid * (V * D4)
                                       + (size_t)u0 * D4 + d4;

    // 256 threads cover 16 u-rows per sweep; 32 sweeps, stride 16 rows = 256 float4.
    #pragma unroll
    for (int k = 0; k < 32; ++k) {
        __builtin_nontemporal_store(val, out4);
        out4 += 16 * D4;
    }
}

extern "C" void kernel_launch(void* const* d_in, const int* in_sizes, int n_in,
                              void* d_out, int out_size, void* d_ws, size_t ws_size,
                              hipStream_t stream) {
    const int*   GE = (const int*)d_in[0];
    const float* W  = (const float*)d_in[1];
    const float* b  = (const float*)d_in[2];
    float* out = (float*)d_out;

    gembed_kernel<<<V * G, 256, 0, stream>>>(GE, W, b, out);
}

// Round 4
// 261.469 us; speedup vs baseline: 1.0239x; 1.0239x over previous
//
#include <hip/hip_runtime.h>
#include <hip/hip_bf16.h>

// out[v,g,u,d] = W[GE[v,g] % 3, d] + b[d], out [V=512, G=4, V=512, D=64] fp32.
// 256 MiB pure writes. Flat grid-stride sweep (rocclr-fill pattern): the
// device-wide write front is one contiguous window -> uniform HBM-channel
// load. Per-block-chunk version phase-aliased channels at 2.9 TB/s.

#define V 512
#define G 4
#define D 64
#define D4 (D / 4)          // 16 fx4 per D-row
#define BIDSHIFT 13         // V*D4 = 8192 fx4 per (v,g) slab
#define NBLK 2048
#define NTHR 256
#define STRIDE (NBLK * NTHR)        // 524288 threads; 16 Mi fx4 total -> 32 iters
#define TOT4 (V * G * V * D4)       // 16777216

typedef float fx4 __attribute__((ext_vector_type(4)));

__global__ __launch_bounds__(NTHR) void gembed_kernel(
    const int* __restrict__ GE,      // [V*G] int32 in [0,3)
    const float* __restrict__ W,     // [3, D]
    const float* __restrict__ b,     // [D]
    float* __restrict__ out)
{
    const int t = blockIdx.x * NTHR + threadIdx.x;   // global thread id
    // STRIDE % 16 == 0, so d4 is constant per thread across iterations.
    const int d4 = t & (D4 - 1);

    const fx4* __restrict__ W4 = (const fx4*)W;  // [3 * D4]
    const fx4* __restrict__ b4 = (const fx4*)b;  // [D4]

    fx4 bb = b4[d4];
    fx4 v0 = W4[0 * D4 + d4] + bb;
    fx4 v1 = W4[1 * D4 + d4] + bb;
    fx4 v2 = W4[2 * D4 + d4] + bb;

    fx4* __restrict__ out4 = (fx4*)out;

    #pragma unroll 4
    for (int idx = t; idx < TOT4; idx += STRIDE) {
        int bid = idx >> BIDSHIFT;               // wave-uniform
        int e = GE[bid];                         // L1-broadcast, values 0..2
        fx4 val = (e == 0) ? v0 : ((e == 1) ? v1 : v2);
        out4[idx] = val;
    }
}

extern "C" void kernel_launch(void* const* d_in, const int* in_sizes, int n_in,
                              void* d_out, int out_size, void* d_ws, size_t ws_size,
                              hipStream_t stream) {
    const int*   GE = (const int*)d_in[0];
    const float* W  = (const float*)d_in[1];
    const float* b  = (const float*)d_in[2];
    float* out = (float*)d_out;

    gembed_kernel<<<NBLK, NTHR, 0, stream>>>(GE, W, b, out);
}